// Round 5
// baseline (94.546 us; speedup 1.0000x reference)
//
#include <hip/hip_runtime.h>

// Problem: B=4, C=19, H=1024, W=1024, N=500000
// out = mean_n [ log(sum_j exp(p_j)) - p_label ],  p = softmax(predict[b,:,r,c])
//
// Structure: (A) coalesced streaming pass computes nll for ALL 4M positions
// into a 16 MB table in d_ws (float4-vectorized, nontemporal input loads so
// the 304 MB predict stream doesn't evict the table from L3), then (B) a
// random 4B gather from the L3-resident table + block reduce, (C) finalize.
//
// NOTE: harness ABI passes ALL integer inputs as int32.
// NOTE: __builtin_nontemporal_load needs clang vector types, not HIP float4
// (HIP_vector_type is a class) -> use ext_vector_type.

#define CCH 19
#define BLOCK 256
#define POS_BITS 20               // H*W = 1<<20
#define TOTAL_POS (4 << POS_BITS) // B * H * W = 4M

typedef float f32x4 __attribute__((ext_vector_type(4)));
typedef int   i32x4 __attribute__((ext_vector_type(4)));

__device__ __forceinline__ float nll_compute(float* __restrict__ x, int label)
{
    float m = x[0];
    #pragma unroll
    for (int j = 1; j < CCH; ++j) m = fmaxf(m, x[j]);

    float s = 0.0f, e_label = 0.0f;
    #pragma unroll
    for (int j = 0; j < CCH; ++j) {
        float e = __expf(x[j] - m);
        s += e;
        if (j == label) e_label = e;   // static j vs runtime label -> cndmask
        x[j] = e;
    }
    float inv = 1.0f / s;

    float s2 = 0.0f;
    #pragma unroll
    for (int j = 0; j < CCH; ++j) s2 += __expf(x[j] * inv);

    return __logf(s2) - e_label * inv;
}

// ---- kernel A: streamed nll table, 4 positions per thread ----
// grid*block*4 == TOTAL_POS exactly (1048576 threads = 4096 blocks) -> no bounds check
__global__ __launch_bounds__(BLOCK) void nll_table_v4(
    const float* __restrict__ predict,
    const int* __restrict__ target,
    float* __restrict__ table)
{
    int q = blockIdx.x * blockDim.x + threadIdx.x;   // quad index
    int i = q << 2;                                  // position index (b*HW + pos)
    int b = i >> POS_BITS;
    int pos = i & ((1 << POS_BITS) - 1);
    const f32x4* base =
        (const f32x4*)(predict + (((size_t)b * CCH) << POS_BITS) + (size_t)pos);

    // 19 channel loads, 16B each, nontemporal (read-once stream, keep L3 for table)
    float xs[4][CCH];                    // statically indexed only -> registers
    #pragma unroll
    for (int j = 0; j < CCH; ++j) {
        f32x4 v = __builtin_nontemporal_load(base + ((size_t)j << 18)); // 4MB/16B
        xs[0][j] = v.x; xs[1][j] = v.y; xs[2][j] = v.z; xs[3][j] = v.w;
    }
    i32x4 lb = __builtin_nontemporal_load((const i32x4*)(target + i));

    f32x4 o;
    o.x = nll_compute(xs[0], lb.x);
    o.y = nll_compute(xs[1], lb.y);
    o.z = nll_compute(xs[2], lb.z);
    o.w = nll_compute(xs[3], lb.w);
    *(f32x4*)(table + i) = o;            // normal store: want it L2/L3 resident
}

// ---- kernel B: random 4B gather from 16MB table + block reduce ----
__global__ __launch_bounds__(BLOCK) void table_gather_kernel(
    const float* __restrict__ table,
    const int* __restrict__ loc_b,
    const int* __restrict__ loc_row,
    const int* __restrict__ loc_col,
    float* __restrict__ partial,
    int n)
{
    int i = blockIdx.x * blockDim.x + threadIdx.x;
    float nll = 0.0f;
    if (i < n) {
        int idx = (loc_b[i] << POS_BITS) + (loc_row[i] << 10) + loc_col[i];
        nll = table[idx];
    }
    __shared__ float red[BLOCK];
    red[threadIdx.x] = nll;
    __syncthreads();
    #pragma unroll
    for (int off = BLOCK / 2; off > 0; off >>= 1) {
        if (threadIdx.x < off) red[threadIdx.x] += red[threadIdx.x + off];
        __syncthreads();
    }
    if (threadIdx.x == 0) partial[blockIdx.x] = red[0];
}

// ---- fallback: direct random gather (round-2 path), used if ws too small ----
__global__ __launch_bounds__(BLOCK) void partial_loss_gather(
    const float* __restrict__ predict,
    const int* __restrict__ target,
    const int* __restrict__ loc_b,
    const int* __restrict__ loc_row,
    const int* __restrict__ loc_col,
    float* __restrict__ partial,
    int n)
{
    int i = blockIdx.x * blockDim.x + threadIdx.x;
    float nll = 0.0f;
    if (i < n) {
        int b = loc_b[i];
        int pos = (loc_row[i] << 10) + loc_col[i];
        const float* base = predict + (((size_t)b * CCH) << POS_BITS) + (size_t)pos;
        int label = target[((size_t)b << POS_BITS) + (size_t)pos];
        float x[CCH];
        #pragma unroll
        for (int j = 0; j < CCH; ++j) x[j] = base[(size_t)j << POS_BITS];
        nll = nll_compute(x, label);
    }
    __shared__ float red[BLOCK];
    red[threadIdx.x] = nll;
    __syncthreads();
    #pragma unroll
    for (int off = BLOCK / 2; off > 0; off >>= 1) {
        if (threadIdx.x < off) red[threadIdx.x] += red[threadIdx.x + off];
        __syncthreads();
    }
    if (threadIdx.x == 0) partial[blockIdx.x] = red[0];
}

__global__ __launch_bounds__(BLOCK) void partial_loss_finalize(
    const float* __restrict__ partial,
    int nparts,
    float* __restrict__ out,
    float inv_n)
{
    __shared__ double red[BLOCK];
    double acc = 0.0;
    for (int i = threadIdx.x; i < nparts; i += BLOCK) acc += (double)partial[i];
    red[threadIdx.x] = acc;
    __syncthreads();
    #pragma unroll
    for (int off = BLOCK / 2; off > 0; off >>= 1) {
        if (threadIdx.x < off) red[threadIdx.x] += red[threadIdx.x + off];
        __syncthreads();
    }
    if (threadIdx.x == 0) out[0] = (float)(red[0] * (double)inv_n);
}

extern "C" void kernel_launch(void* const* d_in, const int* in_sizes, int n_in,
                              void* d_out, int out_size, void* d_ws, size_t ws_size,
                              hipStream_t stream)
{
    const float* predict = (const float*)d_in[0];
    const int*   target  = (const int*)d_in[1];
    const int*   loc_b   = (const int*)d_in[2];
    const int*   loc_row = (const int*)d_in[3];
    const int*   loc_col = (const int*)d_in[4];
    float* out = (float*)d_out;

    int n = in_sizes[2];                         // N = 500000
    int nblocks = (n + BLOCK - 1) / BLOCK;       // 1954

    size_t table_bytes = (size_t)TOTAL_POS * sizeof(float);    // 16 MB
    size_t partial_bytes = (size_t)nblocks * sizeof(float);

    if (ws_size >= table_bytes + partial_bytes) {
        float* table   = (float*)d_ws;
        float* partial = (float*)((char*)d_ws + table_bytes);
        int tblocks = TOTAL_POS / (BLOCK * 4);                 // 4096, exact
        nll_table_v4<<<tblocks, BLOCK, 0, stream>>>(predict, target, table);
        table_gather_kernel<<<nblocks, BLOCK, 0, stream>>>(
            table, loc_b, loc_row, loc_col, partial, n);
        partial_loss_finalize<<<1, BLOCK, 0, stream>>>(
            partial, nblocks, out, 1.0f / (float)n);
    } else {
        float* partial = (float*)d_ws;
        partial_loss_gather<<<nblocks, BLOCK, 0, stream>>>(
            predict, target, loc_b, loc_row, loc_col, partial, n);
        partial_loss_finalize<<<1, BLOCK, 0, stream>>>(
            partial, nblocks, out, 1.0f / (float)n);
    }
}